// Round 1
// baseline (208.355 us; speedup 1.0000x reference)
//
#include <hip/hip_runtime.h>

// Problem constants
#define NROWS 8192   // 4 * 2048
#define DIM   512
#define NT    64                    // 8192 / 128 tiles per side
#define NTRI  (NT * (NT + 1) / 2)   // 2080 upper-triangular tile blocks

using bf16x8 = __attribute__((ext_vector_type(8))) __bf16;
using f32x4  = __attribute__((ext_vector_type(4))) float;

typedef __attribute__((address_space(1))) const void* as1_cvptr;
typedef __attribute__((address_space(3))) void*       as3_vptr;

// async global->LDS, 16B per lane, dest = wave-uniform base + lane*16
__device__ __forceinline__ void async_load16(const void* g, void* l) {
    __builtin_amdgcn_global_load_lds((as1_cvptr)g, (as3_vptr)l, 16, 0, 0);
}

// round-to-nearest-even fp32 -> bf16 bits
__device__ __forceinline__ ushort f2bf(float f) {
    unsigned u = __float_as_uint(f);
    unsigned r = u + 0x7fffu + ((u >> 16) & 1u);
    return (ushort)(r >> 16);
}

// Kernel 1: fp32 row norms + fp32->bf16 conversion; also zeroes accumulator.
// One wave per row (512 elems = 64 lanes x 8).
__global__ __launch_bounds__(256) void norm_convert_kernel(
    const float* __restrict__ X, ushort* __restrict__ Xb,
    float* __restrict__ norms, float* __restrict__ acc)
{
    const int tid  = threadIdx.x;
    const int lane = tid & 63;
    const int w    = tid >> 6;
    const int row  = blockIdx.x * 4 + w;

    if (blockIdx.x == 0 && tid == 0) *acc = 0.0f;

    const float* xr = X + (size_t)row * DIM + lane * 8;
    float4 v0 = *(const float4*)xr;
    float4 v1 = *(const float4*)(xr + 4);

    float s = 0.0f;
    s = fmaf(v0.x, v0.x, s); s = fmaf(v0.y, v0.y, s);
    s = fmaf(v0.z, v0.z, s); s = fmaf(v0.w, v0.w, s);
    s = fmaf(v1.x, v1.x, s); s = fmaf(v1.y, v1.y, s);
    s = fmaf(v1.z, v1.z, s); s = fmaf(v1.w, v1.w, s);

    union { ushort u16[8]; uint4 v; } pk;
    pk.u16[0] = f2bf(v0.x); pk.u16[1] = f2bf(v0.y);
    pk.u16[2] = f2bf(v0.z); pk.u16[3] = f2bf(v0.w);
    pk.u16[4] = f2bf(v1.x); pk.u16[5] = f2bf(v1.y);
    pk.u16[6] = f2bf(v1.z); pk.u16[7] = f2bf(v1.w);
    *(uint4*)(Xb + (size_t)row * DIM + lane * 8) = pk.v;

    #pragma unroll
    for (int off = 32; off > 0; off >>= 1) s += __shfl_down(s, off, 64);
    if (lane == 0) norms[row] = s;
}

// Kernel 2: upper-triangular tiled X·X^T (bf16 MFMA) with fused
// sqrt/exp/sum epilogue. 128x128 tile/block, 4 waves, 64x64 quadrant/wave,
// BK=32 via 16x16x32 MFMA. m97-style staging: global_load_lds width=16.
__global__ __launch_bounds__(256, 1) void pair_loss_gemm_kernel(
    const ushort* __restrict__ Xb, const float* __restrict__ norms,
    float* __restrict__ acc)
{
    __shared__ __align__(16) ushort As[128 * 32];
    __shared__ __align__(16) ushort Bs[128 * 32];

    // decode linear block id -> upper-triangular (bi, bj), bi <= bj
    int t = blockIdx.x, bi = 0;
    while (t >= (NT - bi)) { t -= (NT - bi); bi++; }
    const int bj = bi + t;

    const int tid  = threadIdx.x;
    const int lane = tid & 63;
    const int w    = tid >> 6;

    const int rowA = bi * 128;   // i-tile rows
    const int rowB = bj * 128;   // j-tile rows

    f32x4 accv[4][4];
    const f32x4 zero = {0.0f, 0.0f, 0.0f, 0.0f};
    #pragma unroll
    for (int a = 0; a < 4; a++)
        #pragma unroll
        for (int b = 0; b < 4; b++) accv[a][b] = zero;

    // staging: tile = 128 rows x 32 cols bf16 = 8192B = 512 chunks of 16B.
    // thread handles chunks {tid, tid+256}; chunk c -> row c/4, col (c%4)*8.
    const int c0 = tid, c1 = tid + 256;
    const int r0 = c0 >> 2, r1 = c1 >> 2;
    const int o0 = (c0 & 3) * 8, o1 = (c1 & 3) * 8;
    ushort* ldsA0 = As + w * 512;          // wave-uniform LDS bases
    ushort* ldsA1 = As + w * 512 + 2048;
    ushort* ldsB0 = Bs + w * 512;
    ushort* ldsB1 = Bs + w * 512 + 2048;
    const ushort* gA0 = Xb + (size_t)(rowA + r0) * DIM + o0;
    const ushort* gA1 = Xb + (size_t)(rowA + r1) * DIM + o1;
    const ushort* gB0 = Xb + (size_t)(rowB + r0) * DIM + o0;
    const ushort* gB1 = Xb + (size_t)(rowB + r1) * DIM + o1;

    // MFMA fragment offsets: A[m=lane&15][k=quad*8+j]
    const int fr = lane & 15;
    const int kq = (lane >> 4) * 8;
    const int wr = (w & 1) * 64;   // wave quadrant row base
    const int wc = (w >> 1) * 64;  // wave quadrant col base

    for (int k0 = 0; k0 < DIM; k0 += 32) {
        async_load16(gA0 + k0, ldsA0);
        async_load16(gA1 + k0, ldsA1);
        async_load16(gB0 + k0, ldsB0);
        async_load16(gB1 + k0, ldsB1);
        __syncthreads();   // compiler drains vmcnt before barrier

        bf16x8 af[4], bf[4];
        #pragma unroll
        for (int a = 0; a < 4; a++)
            af[a] = *(const bf16x8*)(As + (wr + a * 16 + fr) * 32 + kq);
        #pragma unroll
        for (int b = 0; b < 4; b++)
            bf[b] = *(const bf16x8*)(Bs + (wc + b * 16 + fr) * 32 + kq);

        #pragma unroll
        for (int a = 0; a < 4; a++)
            #pragma unroll
            for (int b = 0; b < 4; b++)
                accv[a][b] = __builtin_amdgcn_mfma_f32_16x16x32_bf16(
                    af[a], bf[b], accv[a][b], 0, 0, 0);
        __syncthreads();
    }

    // epilogue: term = exp(-0.1*sqrt(max(ni+nj-2*dot, 0))); diag -> 1
    // C/D layout: col = lane&15, row = (lane>>4)*4 + reg
    const float wgt = (bi == bj) ? 1.0f : 2.0f;
    float lsum = 0.0f;
    #pragma unroll
    for (int a = 0; a < 4; a++) {
        const int gi0 = rowA + wr + a * 16 + (lane >> 4) * 4;
        #pragma unroll
        for (int b = 0; b < 4; b++) {
            const int gj = rowB + wc + b * 16 + (lane & 15);
            const float nj = norms[gj];
            #pragma unroll
            for (int r = 0; r < 4; r++) {
                const int gi = gi0 + r;
                float sq = fmaf(-2.0f, accv[a][b][r], norms[gi] + nj);
                sq = fmaxf(sq, 0.0f);
                float term = __expf(-0.1f * sqrtf(sq));
                if (gi == gj) term = 1.0f;
                lsum += term;
            }
        }
    }
    lsum *= wgt;
    #pragma unroll
    for (int off = 32; off > 0; off >>= 1) lsum += __shfl_down(lsum, off, 64);
    if (lane == 0) atomicAdd(acc, lsum);
}

// Kernel 3: finalize scalar outputs
__global__ void finalize_kernel(const float* __restrict__ acc,
                                float* __restrict__ out)
{
    if (threadIdx.x == 0) {
        const float inv = 1.0f / ((float)NROWS * (float)NROWS); // 2^-26 exact
        float loss = (*acc) * inv * 0.1f;
        out[0] = loss;
        out[1] = 0.5f * loss;
    }
}

extern "C" void kernel_launch(void* const* d_in, const int* in_sizes, int n_in,
                              void* d_out, int out_size, void* d_ws, size_t ws_size,
                              hipStream_t stream)
{
    const float* X = (const float*)d_in[0];
    float* out = (float*)d_out;

    char* ws = (char*)d_ws;
    float*  acc   = (float*)ws;                 // [0,4): sum accumulator
    float*  norms = (float*)(ws + 256);         // 8192 fp32 row norms (32 KB)
    ushort* Xb    = (ushort*)(ws + 256 + 32768); // bf16 X, 8 MB, 16B-aligned

    norm_convert_kernel<<<NROWS / 4, 256, 0, stream>>>(X, Xb, norms, acc);
    pair_loss_gemm_kernel<<<NTRI, 256, 0, stream>>>(Xb, norms, acc);
    finalize_kernel<<<1, 64, 0, stream>>>(acc, out);
}

// Round 2
// 120.025 us; speedup vs baseline: 1.7359x; 1.7359x over previous
//
#include <hip/hip_runtime.h>

// Problem constants
#define NROWS 8192   // 4 * 2048
#define DIM   512
#define NT    64                    // 8192 / 128 tiles per side
#define NTRI  (NT * (NT + 1) / 2)   // 2080 upper-triangular tile blocks
#define NACC  64                    // accumulator slots (contention spread)

using bf16x8 = __attribute__((ext_vector_type(8))) __bf16;
using f32x4  = __attribute__((ext_vector_type(4))) float;

// round-to-nearest-even fp32 -> bf16 bits
__device__ __forceinline__ ushort f2bf(float f) {
    unsigned u = __float_as_uint(f);
    unsigned r = u + 0x7fffu + ((u >> 16) & 1u);
    return (ushort)(r >> 16);
}

// Kernel 1: fp32 row norms + fp32->bf16 conversion; zeroes accumulator slots.
// One wave per row (512 elems = 64 lanes x 8).
__global__ __launch_bounds__(256) void norm_convert_kernel(
    const float* __restrict__ X, ushort* __restrict__ Xb,
    float* __restrict__ norms, float* __restrict__ acc)
{
    const int tid  = threadIdx.x;
    const int lane = tid & 63;
    const int w    = tid >> 6;
    const int row  = blockIdx.x * 4 + w;

    if (blockIdx.x == 0 && tid < NACC) acc[tid] = 0.0f;

    const float* xr = X + (size_t)row * DIM + lane * 8;
    float4 v0 = *(const float4*)xr;
    float4 v1 = *(const float4*)(xr + 4);

    float s = 0.0f;
    s = fmaf(v0.x, v0.x, s); s = fmaf(v0.y, v0.y, s);
    s = fmaf(v0.z, v0.z, s); s = fmaf(v0.w, v0.w, s);
    s = fmaf(v1.x, v1.x, s); s = fmaf(v1.y, v1.y, s);
    s = fmaf(v1.z, v1.z, s); s = fmaf(v1.w, v1.w, s);

    union { ushort u16[8]; uint4 v; } pk;
    pk.u16[0] = f2bf(v0.x); pk.u16[1] = f2bf(v0.y);
    pk.u16[2] = f2bf(v0.z); pk.u16[3] = f2bf(v0.w);
    pk.u16[4] = f2bf(v1.x); pk.u16[5] = f2bf(v1.y);
    pk.u16[6] = f2bf(v1.z); pk.u16[7] = f2bf(v1.w);
    *(uint4*)(Xb + (size_t)row * DIM + lane * 8) = pk.v;

    #pragma unroll
    for (int off = 32; off > 0; off >>= 1) s += __shfl_down(s, off, 64);
    if (lane == 0) norms[row] = s;
}

// Kernel 2: upper-triangular tiled X·X^T (bf16 MFMA) with fused
// sqrt/exp/sum epilogue. 128x128 tile/block, 4 waves, 64x64 quadrant/wave,
// BK=32. Register-prefetch double-buffered pipeline (m99-style):
//   top of iter k: issue global loads for k+1 into VGPRs
//   middle:        ds_read frags from cur buf, 16 MFMAs
//   bottom:        ds_write prefetch regs -> next buf, one barrier
// Prefetch is consumed by ds_write BEFORE the barrier, so the barrier's
// vmcnt(0) drain has nothing in flight -> load latency overlaps compute.
__global__ __launch_bounds__(256, 4) void pair_loss_gemm_kernel(
    const ushort* __restrict__ Xb, const float* __restrict__ norms,
    float* __restrict__ acc)
{
    __shared__ __align__(16) ushort As0[128 * 32];
    __shared__ __align__(16) ushort As1[128 * 32];
    __shared__ __align__(16) ushort Bs0[128 * 32];
    __shared__ __align__(16) ushort Bs1[128 * 32];
    __shared__ float wsum[4];

    // decode linear block id -> upper-triangular (bi, bj), bi <= bj
    int t = blockIdx.x, bi = 0;
    while (t >= (NT - bi)) { t -= (NT - bi); bi++; }
    const int bj = bi + t;

    const int tid  = threadIdx.x;
    const int lane = tid & 63;
    const int w    = tid >> 6;

    const int rowA = bi * 128;
    const int rowB = bj * 128;

    f32x4 accv[4][4];
    const f32x4 zero = {0.0f, 0.0f, 0.0f, 0.0f};
    #pragma unroll
    for (int a = 0; a < 4; a++)
        #pragma unroll
        for (int b = 0; b < 4; b++) accv[a][b] = zero;

    // staging mapping: tile = 128 rows x 32 cols bf16 = 512 chunks of 16B.
    // thread -> chunks {tid, tid+256}: rows {tid>>2, tid>>2 + 64}, col (tid&3)*8
    const int r0  = tid >> 2;
    const int o0  = (tid & 3) * 8;
    const int lws = r0 * 32 + o0;   // LDS element offset of chunk 0; chunk 1 at +2048
    const ushort* gA0 = Xb + (size_t)(rowA + r0) * DIM + o0;
    const ushort* gA1 = gA0 + (size_t)64 * DIM;
    const ushort* gB0 = Xb + (size_t)(rowB + r0) * DIM + o0;
    const ushort* gB1 = gB0 + (size_t)64 * DIM;

    // MFMA fragment offsets: A[m=lane&15][k=quad*8+j]
    const int fr = lane & 15;
    const int kq = (lane >> 4) * 8;
    const int wr = (w & 1) * 64;
    const int wc = (w >> 1) * 64;

    // prologue: stage k0=0 through registers
    {
        uint4 pa0 = *(const uint4*)gA0;
        uint4 pa1 = *(const uint4*)gA1;
        uint4 pb0 = *(const uint4*)gB0;
        uint4 pb1 = *(const uint4*)gB1;
        *(uint4*)(As0 + lws)        = pa0;
        *(uint4*)(As0 + lws + 2048) = pa1;
        *(uint4*)(Bs0 + lws)        = pb0;
        *(uint4*)(Bs0 + lws + 2048) = pb1;
    }
    __syncthreads();

    ushort* curA = As0; ushort* nxtA = As1;
    ushort* curB = Bs0; ushort* nxtB = Bs1;

    #pragma unroll 1
    for (int k = 0; k < 16; k++) {
        // prefetch next K-slab into registers (pending during compute)
        uint4 pa0, pa1, pb0, pb1;
        const bool more = (k < 15);
        if (more) {
            const int k0 = (k + 1) * 32;
            pa0 = *(const uint4*)(gA0 + k0);
            pa1 = *(const uint4*)(gA1 + k0);
            pb0 = *(const uint4*)(gB0 + k0);
            pb1 = *(const uint4*)(gB1 + k0);
        }

        bf16x8 af[4], bfr[4];
        #pragma unroll
        for (int a = 0; a < 4; a++)
            af[a] = *(const bf16x8*)(curA + (wr + a * 16 + fr) * 32 + kq);
        #pragma unroll
        for (int b = 0; b < 4; b++)
            bfr[b] = *(const bf16x8*)(curB + (wc + b * 16 + fr) * 32 + kq);

        #pragma unroll
        for (int a = 0; a < 4; a++)
            #pragma unroll
            for (int b = 0; b < 4; b++)
                accv[a][b] = __builtin_amdgcn_mfma_f32_16x16x32_bf16(
                    af[a], bfr[b], accv[a][b], 0, 0, 0);

        if (more) {
            *(uint4*)(nxtA + lws)        = pa0;  // waits vmcnt for prefetch here
            *(uint4*)(nxtA + lws + 2048) = pa1;
            *(uint4*)(nxtB + lws)        = pb0;
            *(uint4*)(nxtB + lws + 2048) = pb1;
            __syncthreads();
            ushort* tA = curA; curA = nxtA; nxtA = tA;
            ushort* tB = curB; curB = nxtB; nxtB = tB;
        }
    }

    // epilogue: term = exp(-0.1*sqrt(max(ni+nj-2*dot, 0))); diag -> 1
    // C/D layout: col = lane&15, row = (lane>>4)*4 + reg
    const float wgt = (bi == bj) ? 1.0f : 2.0f;
    float lsum = 0.0f;
    #pragma unroll
    for (int a = 0; a < 4; a++) {
        const int gi0 = rowA + wr + a * 16 + (lane >> 4) * 4;
        #pragma unroll
        for (int b = 0; b < 4; b++) {
            const int gj = rowB + wc + b * 16 + (lane & 15);
            const float nj = norms[gj];
            #pragma unroll
            for (int r = 0; r < 4; r++) {
                const int gi = gi0 + r;
                float sq = fmaf(-2.0f, accv[a][b][r], norms[gi] + nj);
                sq = fmaxf(sq, 0.0f);
                float term = __expf(-0.1f * sqrtf(sq));
                if (gi == gj) term = 1.0f;
                lsum += term;
            }
        }
    }
    lsum *= wgt;
    #pragma unroll
    for (int off = 32; off > 0; off >>= 1) lsum += __shfl_down(lsum, off, 64);
    if (lane == 0) wsum[w] = lsum;
    __syncthreads();
    if (tid == 0)
        atomicAdd(&acc[blockIdx.x & (NACC - 1)],
                  wsum[0] + wsum[1] + wsum[2] + wsum[3]);
}

// Kernel 3: finalize scalar outputs (sum NACC slots)
__global__ void finalize_kernel(const float* __restrict__ acc,
                                float* __restrict__ out)
{
    const int lane = threadIdx.x;
    float s = (lane < NACC) ? acc[lane] : 0.0f;
    #pragma unroll
    for (int off = 32; off > 0; off >>= 1) s += __shfl_down(s, off, 64);
    if (lane == 0) {
        const float inv = 1.0f / ((float)NROWS * (float)NROWS); // 2^-26 exact
        float loss = s * inv * 0.1f;
        out[0] = loss;
        out[1] = 0.5f * loss;
    }
}

extern "C" void kernel_launch(void* const* d_in, const int* in_sizes, int n_in,
                              void* d_out, int out_size, void* d_ws, size_t ws_size,
                              hipStream_t stream)
{
    const float* X = (const float*)d_in[0];
    float* out = (float*)d_out;

    char* ws = (char*)d_ws;
    float*  acc   = (float*)ws;                  // NACC fp32 slots
    float*  norms = (float*)(ws + 1024);         // 8192 fp32 row norms (32 KB)
    ushort* Xb    = (ushort*)(ws + 1024 + 32768); // bf16 X, 8 MB, 16B-aligned

    norm_convert_kernel<<<NROWS / 4, 256, 0, stream>>>(X, Xb, norms, acc);
    pair_loss_gemm_kernel<<<NTRI, 256, 0, stream>>>(Xb, norms, acc);
    finalize_kernel<<<1, 64, 0, stream>>>(acc, out);
}